// Round 7
// baseline (207.980 us; speedup 1.0000x reference)
//
#include <hip/hip_runtime.h>
#include <math.h>

// Problem constants
#define KS    11
#define H     512
#define W     512
#define OH    502
#define OW    502
#define NPLANES 48
#define TOTAL_OUT (NPLANES * OH * OW)   // 12,096,192

// 256-thread blocks, 2 column tiles (256+10-halo / 256), TH=4 rows/iter, 4 signals.
// Register ring: 14-row window slides by 4 -> 8 global loads/iter (main pass).
#define TH      4
#define IROWS   (TH + KS - 1)     // 14 input rows in the register window
#define NSIG    4                 // mu_x, mu_y, conv(x^2+y^2), conv(xy)
#define HALO    10
#define LVW     267               // ODD stride (words), 267 % 32 == 11 -> conflict-free algebra
#define NTHREADS 256
#define CHUNK   32                // output rows per block
#define NCHUNKS 16                // 16*32 = 512 >= 502

__global__ void zero_out_kernel(float* out) { out[0] = 0.0f; }

__device__ __forceinline__ float uniform_f(float v) {
    // v is wave-uniform; route through readfirstlane to place it in an SGPR.
    return __int_as_float(__builtin_amdgcn_readfirstlane(__float_as_int(v)));
}

// block=256: 2nd arg = 6 blocks/CU under either launch_bounds semantics -> 85-VGPR budget.
// 6 blocks x 17.1 KB LDS = 103 KB < 160 KB; 6 x 4 waves = 24 waves/CU, all 1536 blocks resident.
__global__ __launch_bounds__(NTHREADS, 6) void ssim_kernel(
    const float* __restrict__ x,
    const float* __restrict__ y,
    const float* __restrict__ win,
    float* __restrict__ out)
{
    __shared__ float v[NSIG][TH][LVW];   // 17,088 B -> 6 blocks/CU
    __shared__ float w1s[KS];
    __shared__ float wsum[NTHREADS / 64];

    const int t     = threadIdx.x;
    const int tile  = blockIdx.x & 1;       // 0: out cols 0..255 (+halo), 1: out cols 256..501
    const int chunk = blockIdx.x >> 1;      // 0..15
    const int plane = blockIdx.y;           // 0..47

    const int in_base = tile << 8;                       // 0 or 256
    const int tile_w  = tile ? (OW - 256) : 256;         // 246 or 256

    const int row_lo = chunk * CHUNK;
    const int row_hi = (row_lo + CHUNK < OH) ? (row_lo + CHUNK) : OH;
    const int niter  = (row_hi - row_lo + TH - 1) / TH;  // 8 (chunks 0-14), 6 (chunk 15)

    const float* __restrict__ xp = x + (size_t)plane * (H * W);
    const float* __restrict__ yp = y + (size_t)plane * (H * W);

    // Separable taps: window = outer(g,g) => g[i] = sqrt(win[i][i])
    if (t < KS) w1s[t] = sqrtf(win[t * KS + t]);
    __syncthreads();

    // Taps are wave-uniform -> SGPRs (measured: saved 11+ VGPRs in r6).
    float w[KS];
#pragma unroll
    for (int k = 0; k < KS; k++) w[k] = uniform_f(w1s[k]);

    // Stage-2 mapping (measured conflict-free class, r4/r6): 4 rows x 64 runs of 4 px.
    // bank = (11r + 4(u%8) + j) mod 32 -> all 32 banks, 2 lanes each = free.
    const int r  = t & 3;
    const int c0 = (t >> 2) << 2;            // 0..252; reads words c0..c0+13 <= 265 < 267
    const float c1 = 1e-4f;   // (0.01)^2
    const float c2 = 9e-4f;   // (0.03)^2
    float acc = 0.f;

    const int gx = in_base + t;              // main column, always < 512

    // ---- Prime the register ring: rows row_lo..row_lo+13 (<= 493, in range) ----
    float rx[IROWS], ry[IROWS];
#pragma unroll
    for (int j = 0; j < IROWS; j++) {
        int gy = row_lo + j; gy = (gy < H - 1) ? gy : (H - 1);
        rx[j] = xp[gy * W + gx];
        ry[j] = yp[gy * W + gx];
    }

    for (int it = 0; it < niter; ++it) {
        const int gy0 = row_lo + it * TH;

        // ---- Stage 1 (main): vertical 11-tap conv from the register window ----
        float a0[TH], a1[TH], a2[TH], a3[TH];
#pragma unroll
        for (int q = 0; q < TH; q++) { a0[q]=0.f; a1[q]=0.f; a2[q]=0.f; a3[q]=0.f; }

#pragma unroll
        for (int j = 0; j < IROWS; j++) {
            const float xv = rx[j], yv = ry[j];
            const float pss = xv * xv + yv * yv;   // fused x^2+y^2 signal
            const float pxy = xv * yv;
#pragma unroll
            for (int q = 0; q < TH; q++) {
                if (j - q >= 0 && j - q < KS) {    // constant-folds after unroll
                    const float wk = w[j - q];
                    a0[q] += wk * xv;
                    a1[q] += wk * yv;
                    a2[q] += wk * pss;
                    a3[q] += wk * pxy;
                }
            }
        }

        __syncthreads();    // barrier 1: previous iteration's stage-2 reads of v are done
#pragma unroll
        for (int q = 0; q < TH; q++) {      // lane==col -> stride-1 words -> conflict-free
            v[0][q][t] = a0[q];
            v[1][q][t] = a1[q];
            v[2][q][t] = a2[q];
            v[3][q][t] = a3[q];
        }

        // ---- Halo pass (tile 0 only, lanes 0..9 of wave 0): vconv for cols 256..265 ----
        // Exec-masked; costs issue slots in 1 wave of half the blocks (~+4% average).
        // a0..a3 are dead here (written), so temps reuse their registers.
        if (tile == 0 && t < HALO) {
            const int gxb = 256 + t;
            float b0[TH], b1[TH], b2[TH], b3[TH];
#pragma unroll
            for (int q = 0; q < TH; q++) { b0[q]=0.f; b1[q]=0.f; b2[q]=0.f; b3[q]=0.f; }
            float hx[IROWS], hy[IROWS];
#pragma unroll
            for (int j = 0; j < IROWS; j++) {   // issue all loads first, then FMA
                int gy = gy0 + j; gy = (gy < H - 1) ? gy : (H - 1);
                hx[j] = xp[gy * W + gxb];
                hy[j] = yp[gy * W + gxb];
            }
#pragma unroll
            for (int j = 0; j < IROWS; j++) {
                const float xv = hx[j], yv = hy[j];
                const float pss = xv * xv + yv * yv;
                const float pxy = xv * yv;
#pragma unroll
                for (int q = 0; q < TH; q++) {
                    if (j - q >= 0 && j - q < KS) {
                        const float wk = w[j - q];
                        b0[q] += wk * xv;
                        b1[q] += wk * yv;
                        b2[q] += wk * pss;
                        b3[q] += wk * pxy;
                    }
                }
            }
#pragma unroll
            for (int q = 0; q < TH; q++) {
                v[0][q][256 + t] = b0[q];
                v[1][q][256 + t] = b1[q];
                v[2][q][256 + t] = b2[q];
                v[3][q][256 + t] = b3[q];
            }
        }
        __syncthreads();    // barrier 2: v ready (tile-1 halo words stay unwritten;
                            // taps for surviving outputs never reach word >= 256 there)

        // ---- Slide the ring + prefetch 4 new rows per image (8 loads) ----
        // First use is NEXT iteration's vconv; no barrier between issue and use.
        if (it + 1 < niter) {
#pragma unroll
            for (int j = 0; j < IROWS - TH; j++) {
                rx[j] = rx[j + TH];
                ry[j] = ry[j + TH];
            }
#pragma unroll
            for (int j = 0; j < TH; j++) {
                int gy = gy0 + IROWS + j;            // rows gy0+14..gy0+17
                gy = (gy < H - 1) ? gy : (H - 1);    // clamp feeds only discarded rows
                rx[IROWS - TH + j] = xp[gy * W + gx];
                ry[IROWS - TH + j] = yp[gy * W + gx];
            }
        }

        // ---- Stage 2: horizontal 11-tap conv over 4-px run + SSIM ----
        float mu[NSIG][TH];
#pragma unroll
        for (int s = 0; s < NSIG; s++) {
            const float* __restrict__ vrow = &v[s][r][c0];
            float vs[IROWS];
#pragma unroll
            for (int j = 0; j < IROWS; j++) vs[j] = vrow[j];   // b32/ds_read2, conflict-free
#pragma unroll
            for (int p = 0; p < TH; p++) {
                float m = 0.f;
#pragma unroll
                for (int k = 0; k < KS; k++) m += w[k] * vs[p + k];
                mu[s][p] = m;
            }
        }

        const int grow  = gy0 + r;
        const bool rowok = (grow < row_hi);
#pragma unroll
        for (int p = 0; p < TH; p++) {
            if (rowok && (c0 + p) < tile_w) {
                const float mux = mu[0][p], muy = mu[1][p];
                const float mxy = mux * muy;
                const float m2  = mux * mux + muy * muy;
                const float sss = mu[2][p] - m2;        // sigma_x^2 + sigma_y^2
                const float sxy = mu[3][p] - mxy;
                const float num = (2.f * sxy + c2) * (2.f * mxy + c1);
                const float den = (sss + c2) * (m2 + c1);
                acc += num * __builtin_amdgcn_rcpf(den);
            }
        }
    }

    // ---- Reduction: wave shuffle -> cross-wave LDS -> one atomic/block ----
#pragma unroll
    for (int off = 32; off > 0; off >>= 1)
        acc += __shfl_down(acc, off, 64);

    if ((t & 63) == 0) wsum[t >> 6] = acc;
    __syncthreads();
    if (t == 0) {
        float s = 0.f;
#pragma unroll
        for (int i = 0; i < NTHREADS / 64; i++) s += wsum[i];
        atomicAdd(out, s * (1.0f / (float)TOTAL_OUT));
    }
}

extern "C" void kernel_launch(void* const* d_in, const int* in_sizes, int n_in,
                              void* d_out, int out_size, void* d_ws, size_t ws_size,
                              hipStream_t stream)
{
    const float* x   = (const float*)d_in[0];
    const float* y   = (const float*)d_in[1];
    const float* win = (const float*)d_in[2];
    float* out = (float*)d_out;

    zero_out_kernel<<<1, 1, 0, stream>>>(out);

    // (2 tiles x 16 chunks, 48 planes) = 1536 blocks = 6/CU x 256 CUs exactly:
    // all resident from t=0, 6 independent 4-wave barrier domains per CU.
    dim3 grid(2 * NCHUNKS, NPLANES);
    ssim_kernel<<<grid, NTHREADS, 0, stream>>>(x, y, win, out);
}

// Round 8
// 192.822 us; speedup vs baseline: 1.0786x; 1.0786x over previous
//
#include <hip/hip_runtime.h>
#include <math.h>

// Problem constants
#define KS    11
#define H     512
#define W     512
#define OH    502
#define OW    502
#define NPLANES 48
#define TOTAL_OUT (NPLANES * OH * OW)   // 12,096,192

// 256-thread blocks, 2 column tiles (256+10-halo / 256), TH=4 rows/iter, 4 signals.
// Register ring: 14-row window slides by 4 -> 8 global loads/iter (main pass).
#define TH      4
#define IROWS   (TH + KS - 1)     // 14 input rows in the register window
#define NSIG    4                 // mu_x, mu_y, conv(x^2+y^2), conv(xy)
#define HALO    10
#define LVW     267               // ODD stride (words), 267 % 32 == 11 -> conflict-free algebra
#define NTHREADS 256
#define CHUNK   32                // output rows per block
#define NCHUNKS 16                // 16*32 = 512 >= 502

__global__ void zero_out_kernel(float* out) { out[0] = 0.0f; }

__device__ __forceinline__ float uniform_f(float v) {
    // v is wave-uniform; route through readfirstlane to place it in an SGPR.
    return __int_as_float(__builtin_amdgcn_readfirstlane(__float_as_int(v)));
}

// EMPIRICAL launch_bounds 2nd-arg semantics on this compiler (r1/r2/r7 calibration):
// VGPR cap ~= 256/arg, INDEPENDENT of block size: (512,6)->40, (256,6)->40, (512,3)->84.
// Natural usage here ~60-75 -> arg=3 (cap 84) avoids spill; actual usage <=84 still
// yields 6 waves/SIMD (512/84 -> 6) = 24 waves/CU; LDS 6 x 17.1 KB = 103 KB fits.
__global__ __launch_bounds__(NTHREADS, 3) void ssim_kernel(
    const float* __restrict__ x,
    const float* __restrict__ y,
    const float* __restrict__ win,
    float* __restrict__ out)
{
    __shared__ float v[NSIG][TH][LVW];   // 17,088 B -> 6 blocks/CU
    __shared__ float w1s[KS];
    __shared__ float wsum[NTHREADS / 64];

    const int t     = threadIdx.x;
    const int tile  = blockIdx.x & 1;       // 0: out cols 0..255 (+halo), 1: out cols 256..501
    const int chunk = blockIdx.x >> 1;      // 0..15
    const int plane = blockIdx.y;           // 0..47

    const int in_base = tile << 8;                       // 0 or 256
    const int tile_w  = tile ? (OW - 256) : 256;         // 246 or 256

    const int row_lo = chunk * CHUNK;
    const int row_hi = (row_lo + CHUNK < OH) ? (row_lo + CHUNK) : OH;
    const int niter  = (row_hi - row_lo + TH - 1) / TH;  // 8 (chunks 0-14), 6 (chunk 15)

    const float* __restrict__ xp = x + (size_t)plane * (H * W);
    const float* __restrict__ yp = y + (size_t)plane * (H * W);

    // Separable taps: window = outer(g,g) => g[i] = sqrt(win[i][i])
    if (t < KS) w1s[t] = sqrtf(win[t * KS + t]);
    __syncthreads();

    // Taps are wave-uniform -> SGPRs (measured: saved 11+ VGPRs in r6).
    float w[KS];
#pragma unroll
    for (int k = 0; k < KS; k++) w[k] = uniform_f(w1s[k]);

    // Stage-2 mapping (measured conflict-free class, r4/r6): 4 rows x 64 runs of 4 px.
    // bank = (11r + 4(u%8) + j) mod 32 -> all 32 banks, 2 lanes each = free.
    const int r  = t & 3;
    const int c0 = (t >> 2) << 2;            // 0..252; reads words c0..c0+13 <= 265 < 267
    const float c1 = 1e-4f;   // (0.01)^2
    const float c2 = 9e-4f;   // (0.03)^2
    float acc = 0.f;

    const int gx = in_base + t;              // main column, always < 512

    // ---- Prime the register ring: rows row_lo..row_lo+13 (<= 493, in range) ----
    float rx[IROWS], ry[IROWS];
#pragma unroll
    for (int j = 0; j < IROWS; j++) {
        int gy = row_lo + j; gy = (gy < H - 1) ? gy : (H - 1);
        rx[j] = xp[gy * W + gx];
        ry[j] = yp[gy * W + gx];
    }

    for (int it = 0; it < niter; ++it) {
        const int gy0 = row_lo + it * TH;

        // ---- Stage 1 (main): vertical 11-tap conv from the register window ----
        float a0[TH], a1[TH], a2[TH], a3[TH];
#pragma unroll
        for (int q = 0; q < TH; q++) { a0[q]=0.f; a1[q]=0.f; a2[q]=0.f; a3[q]=0.f; }

#pragma unroll
        for (int j = 0; j < IROWS; j++) {
            const float xv = rx[j], yv = ry[j];
            const float pss = xv * xv + yv * yv;   // fused x^2+y^2 signal
            const float pxy = xv * yv;
#pragma unroll
            for (int q = 0; q < TH; q++) {
                if (j - q >= 0 && j - q < KS) {    // constant-folds after unroll
                    const float wk = w[j - q];
                    a0[q] += wk * xv;
                    a1[q] += wk * yv;
                    a2[q] += wk * pss;
                    a3[q] += wk * pxy;
                }
            }
        }

        __syncthreads();    // barrier 1: previous iteration's stage-2 reads of v are done
#pragma unroll
        for (int q = 0; q < TH; q++) {      // lane==col -> stride-1 words -> conflict-free
            v[0][q][t] = a0[q];
            v[1][q][t] = a1[q];
            v[2][q][t] = a2[q];
            v[3][q][t] = a3[q];
        }

        // ---- Halo pass (tile 0 only, lanes 0..9 of wave 0): vconv for cols 256..265 ----
        // Exec-masked, register-lean: per-row load is immediately consumed (no 28-reg
        // hx/hy arrays) to stay under the 84-VGPR cap. Latency hits only 10 lanes of
        // one wave; the other 23 resident waves cover it.
        if (tile == 0 && t < HALO) {
            const int gxb = 256 + t;
            float b0[TH], b1[TH], b2[TH], b3[TH];
#pragma unroll
            for (int q = 0; q < TH; q++) { b0[q]=0.f; b1[q]=0.f; b2[q]=0.f; b3[q]=0.f; }
#pragma unroll
            for (int j = 0; j < IROWS; j++) {
                int gy = gy0 + j; gy = (gy < H - 1) ? gy : (H - 1);
                const float xv = xp[gy * W + gxb];
                const float yv = yp[gy * W + gxb];
                const float pss = xv * xv + yv * yv;
                const float pxy = xv * yv;
#pragma unroll
                for (int q = 0; q < TH; q++) {
                    if (j - q >= 0 && j - q < KS) {
                        const float wk = w[j - q];
                        b0[q] += wk * xv;
                        b1[q] += wk * yv;
                        b2[q] += wk * pss;
                        b3[q] += wk * pxy;
                    }
                }
            }
#pragma unroll
            for (int q = 0; q < TH; q++) {
                v[0][q][256 + t] = b0[q];
                v[1][q][256 + t] = b1[q];
                v[2][q][256 + t] = b2[q];
                v[3][q][256 + t] = b3[q];
            }
        }
        __syncthreads();    // barrier 2: v ready (tile-1 halo words stay unwritten;
                            // guarded outputs there never read past word 255)

        // ---- Slide the ring + prefetch 4 new rows per image (8 loads) ----
        // First use is NEXT iteration's vconv; no barrier between issue and use.
        if (it + 1 < niter) {
#pragma unroll
            for (int j = 0; j < IROWS - TH; j++) {
                rx[j] = rx[j + TH];
                ry[j] = ry[j + TH];
            }
#pragma unroll
            for (int j = 0; j < TH; j++) {
                int gy = gy0 + IROWS + j;            // rows gy0+14..gy0+17
                gy = (gy < H - 1) ? gy : (H - 1);    // clamp feeds only discarded rows
                rx[IROWS - TH + j] = xp[gy * W + gx];
                ry[IROWS - TH + j] = yp[gy * W + gx];
            }
        }

        // ---- Stage 2: horizontal 11-tap conv over 4-px run + SSIM ----
        float mu[NSIG][TH];
#pragma unroll
        for (int s = 0; s < NSIG; s++) {
            const float* __restrict__ vrow = &v[s][r][c0];
            float vs[IROWS];
#pragma unroll
            for (int j = 0; j < IROWS; j++) vs[j] = vrow[j];   // b32/ds_read2, conflict-free
#pragma unroll
            for (int p = 0; p < TH; p++) {
                float m = 0.f;
#pragma unroll
                for (int k = 0; k < KS; k++) m += w[k] * vs[p + k];
                mu[s][p] = m;
            }
        }

        const int grow  = gy0 + r;
        const bool rowok = (grow < row_hi);
#pragma unroll
        for (int p = 0; p < TH; p++) {
            if (rowok && (c0 + p) < tile_w) {
                const float mux = mu[0][p], muy = mu[1][p];
                const float mxy = mux * muy;
                const float m2  = mux * mux + muy * muy;
                const float sss = mu[2][p] - m2;        // sigma_x^2 + sigma_y^2
                const float sxy = mu[3][p] - mxy;
                const float num = (2.f * sxy + c2) * (2.f * mxy + c1);
                const float den = (sss + c2) * (m2 + c1);
                acc += num * __builtin_amdgcn_rcpf(den);
            }
        }
    }

    // ---- Reduction: wave shuffle -> cross-wave LDS -> one atomic/block ----
#pragma unroll
    for (int off = 32; off > 0; off >>= 1)
        acc += __shfl_down(acc, off, 64);

    if ((t & 63) == 0) wsum[t >> 6] = acc;
    __syncthreads();
    if (t == 0) {
        float s = 0.f;
#pragma unroll
        for (int i = 0; i < NTHREADS / 64; i++) s += wsum[i];
        atomicAdd(out, s * (1.0f / (float)TOTAL_OUT));
    }
}

extern "C" void kernel_launch(void* const* d_in, const int* in_sizes, int n_in,
                              void* d_out, int out_size, void* d_ws, size_t ws_size,
                              hipStream_t stream)
{
    const float* x   = (const float*)d_in[0];
    const float* y   = (const float*)d_in[1];
    const float* win = (const float*)d_in[2];
    float* out = (float*)d_out;

    zero_out_kernel<<<1, 1, 0, stream>>>(out);

    // (2 tiles x 16 chunks, 48 planes) = 1536 blocks = 6/CU x 256 CUs exactly:
    // all resident from t=0, 6 independent 4-wave barrier domains per CU.
    dim3 grid(2 * NCHUNKS, NPLANES);
    ssim_kernel<<<grid, NTHREADS, 0, stream>>>(x, y, win, out);
}

// Round 9
// 151.102 us; speedup vs baseline: 1.3764x; 1.2761x over previous
//
#include <hip/hip_runtime.h>
#include <math.h>

// Problem constants
#define KS    11
#define H     512
#define W     512
#define OH    502
#define OW    502
#define NPLANES 48
#define TOTAL_OUT (NPLANES * OH * OW)   // 12,096,192

// Full-width 512-thread blocks, TH=4 output rows/iter, 4 signals (xx+yy fused).
// Register ring-buffer: 14-row window slides by 4 -> 8 global loads/iter.
// Round 9: same compute as r6 (64.5 us), regridded for 4 blocks/CU residency.
#define TH      4
#define IROWS   (TH + KS - 1)     // 14 input rows in the register window
#define NSIG    4                 // mu_x, mu_y, conv(x^2+y^2), conv(xy)
#define LVW     523               // ODD stride (words), 523 % 32 == 11 -> conflict-free algebra
#define NTHREADS 512
#define CHUNK   24                // output rows per block (21 chunks x 24 = 504 >= 502)
#define NCHUNKS 21

__global__ void zero_out_kernel(float* out) { out[0] = 0.0f; }

__device__ __forceinline__ float uniform_f(float v) {
    // v is wave-uniform; route through readfirstlane to place it in an SGPR.
    return __int_as_float(__builtin_amdgcn_readfirstlane(__float_as_int(v)));
}

// EMPIRICAL launch_bounds 2nd-arg law on this compiler (r1/r2/r7 calibration):
// VGPR cap ~= 256/arg, independent of block size: (512,6)->40, (256,6)->40, (512,3)->84.
// arg=4 -> cap 64 >= measured natural usage 52 (r6/r8) -> no spill, and <=64 regs keeps
// the 8-waves/SIMD occupancy step: 4 blocks x 8 waves = 32 waves/CU (LDS 4x33.5=134KB fits).
__global__ __launch_bounds__(NTHREADS, 4) void ssim_kernel(
    const float* __restrict__ x,
    const float* __restrict__ y,
    const float* __restrict__ win,
    float* __restrict__ out)
{
    __shared__ float v[NSIG][TH][LVW];   // 33,472 B -> 4 blocks/CU
    __shared__ float w1s[KS];
    __shared__ float wsum[NTHREADS / 64];

    const int t     = threadIdx.x;          // == input column
    const int chunk = blockIdx.x;           // 0..20
    const int plane = blockIdx.y;           // 0..47

    const int row_lo = chunk * CHUNK;
    const int row_hi = (row_lo + CHUNK < OH) ? (row_lo + CHUNK) : OH;
    const int niter  = (row_hi - row_lo + TH - 1) / TH;   // 6 for all chunks

    const float* __restrict__ xp = x + (size_t)plane * (H * W);
    const float* __restrict__ yp = y + (size_t)plane * (H * W);

    // Separable taps: window = outer(g,g) => g[i] = sqrt(win[i][i])
    if (t < KS) w1s[t] = sqrtf(win[t * KS + t]);
    __syncthreads();

    // Taps are wave-uniform -> SGPRs (measured: saved 11+ VGPRs, r6).
    float w[KS];
#pragma unroll
    for (int k = 0; k < KS; k++) w[k] = uniform_f(w1s[k]);

    // Stage-2 mapping (measured conflict-free, r4/r6/r8): 4 rows x 128 runs of 4 px.
    // bank = (11r + 4(u%8) + j) mod 32 -> all 32 banks, 2 lanes each = free.
    const int r  = t & 3;
    const int c0 = (t >> 2) << 2;            // 0..508; reads words c0..c0+13 <= 521 < 523
    const float c1 = 1e-4f;   // (0.01)^2
    const float c2 = 9e-4f;   // (0.03)^2
    float acc = 0.f;

    // ---- Prime the register ring: rows row_lo..row_lo+13 (<= 493, in range) ----
    float rx[IROWS], ry[IROWS];
#pragma unroll
    for (int j = 0; j < IROWS; j++) {
        int gy = row_lo + j; gy = (gy < H - 1) ? gy : (H - 1);
        rx[j] = xp[gy * W + t];
        ry[j] = yp[gy * W + t];
    }

    for (int it = 0; it < niter; ++it) {
        const int gy0 = row_lo + it * TH;

        // ---- Stage 1: vertical 11-tap conv from the register window ----
        float a0[TH], a1[TH], a2[TH], a3[TH];
#pragma unroll
        for (int q = 0; q < TH; q++) { a0[q]=0.f; a1[q]=0.f; a2[q]=0.f; a3[q]=0.f; }

#pragma unroll
        for (int j = 0; j < IROWS; j++) {
            const float xv = rx[j], yv = ry[j];
            const float pss = xv * xv + yv * yv;   // fused x^2+y^2 signal
            const float pxy = xv * yv;
#pragma unroll
            for (int q = 0; q < TH; q++) {
                if (j - q >= 0 && j - q < KS) {    // constant-folds after unroll
                    const float wk = w[j - q];
                    a0[q] += wk * xv;
                    a1[q] += wk * yv;
                    a2[q] += wk * pss;
                    a3[q] += wk * pxy;
                }
            }
        }

        __syncthreads();    // barrier 1: previous iteration's stage-2 reads of v are done
#pragma unroll
        for (int q = 0; q < TH; q++) {      // lane==col -> stride-1 words -> conflict-free
            v[0][q][t] = a0[q];
            v[1][q][t] = a1[q];
            v[2][q][t] = a2[q];
            v[3][q][t] = a3[q];
        }
        __syncthreads();    // barrier 2: v ready

        // ---- Slide the ring + prefetch 4 new rows per image (8 loads) ----
        // First use is NEXT iteration's vconv; no barrier between issue and use,
        // so the vmcnt(0)-before-s_barrier drain never exposes these loads.
        if (it + 1 < niter) {
#pragma unroll
            for (int j = 0; j < IROWS - TH; j++) {
                rx[j] = rx[j + TH];
                ry[j] = ry[j + TH];
            }
#pragma unroll
            for (int j = 0; j < TH; j++) {
                int gy = gy0 + IROWS + j;            // rows gy0+14..gy0+17
                gy = (gy < H - 1) ? gy : (H - 1);    // clamp feeds only discarded rows
                rx[IROWS - TH + j] = xp[gy * W + t];
                ry[IROWS - TH + j] = yp[gy * W + t];
            }
        }

        // ---- Stage 2: horizontal 11-tap conv over 4-px run + SSIM ----
        float mu[NSIG][TH];
#pragma unroll
        for (int s = 0; s < NSIG; s++) {
            const float* __restrict__ vrow = &v[s][r][c0];
            float vs[IROWS];
#pragma unroll
            for (int j = 0; j < IROWS; j++) vs[j] = vrow[j];   // b32/ds_read2, conflict-free
#pragma unroll
            for (int p = 0; p < TH; p++) {
                float m = 0.f;
#pragma unroll
                for (int k = 0; k < KS; k++) m += w[k] * vs[p + k];
                mu[s][p] = m;
            }
        }

        const int grow  = gy0 + r;
        const bool rowok = (grow < row_hi);
#pragma unroll
        for (int p = 0; p < TH; p++) {
            if (rowok && (c0 + p) < OW) {
                const float mux = mu[0][p], muy = mu[1][p];
                const float mxy = mux * muy;
                const float m2  = mux * mux + muy * muy;
                const float sss = mu[2][p] - m2;        // sigma_x^2 + sigma_y^2
                const float sxy = mu[3][p] - mxy;
                const float num = (2.f * sxy + c2) * (2.f * mxy + c1);
                const float den = (sss + c2) * (m2 + c1);
                acc += num * __builtin_amdgcn_rcpf(den);
            }
        }
    }

    // ---- Reduction: wave shuffle -> cross-wave LDS -> one atomic/block ----
#pragma unroll
    for (int off = 32; off > 0; off >>= 1)
        acc += __shfl_down(acc, off, 64);

    if ((t & 63) == 0) wsum[t >> 6] = acc;
    __syncthreads();
    if (t == 0) {
        float s = 0.f;
#pragma unroll
        for (int i = 0; i < NTHREADS / 64; i++) s += wsum[i];
        atomicAdd(out, s * (1.0f / (float)TOTAL_OUT));
    }
}

extern "C" void kernel_launch(void* const* d_in, const int* in_sizes, int n_in,
                              void* d_out, int out_size, void* d_ws, size_t ws_size,
                              hipStream_t stream)
{
    const float* x   = (const float*)d_in[0];
    const float* y   = (const float*)d_in[1];
    const float* win = (const float*)d_in[2];
    float* out = (float*)d_out;

    zero_out_kernel<<<1, 1, 0, stream>>>(out);

    // (21 chunks, 48 planes) = 1008 blocks ~= 4/CU x 256 CUs in a SINGLE round
    // (240 CUs host 4 blocks, 16 host 3) -> 4 independent 8-wave barrier domains/CU.
    dim3 grid(NCHUNKS, NPLANES);
    ssim_kernel<<<grid, NTHREADS, 0, stream>>>(x, y, win, out);
}